// Round 3
// baseline (21420.453 us; speedup 1.0000x reference)
//
#include <hip/hip_runtime.h>
#include <hip/hip_bf16.h>
#include <stdint.h>

typedef __bf16   bf16x8 __attribute__((ext_vector_type(8)));
typedef float    f32x4  __attribute__((ext_vector_type(4)));
typedef float    fl4    __attribute__((ext_vector_type(4)));
typedef uint32_t u32;
typedef unsigned long long u64;
typedef uint32_t u32x4  __attribute__((ext_vector_type(4)));

#define T_    1024
#define G4H   2048

__device__ __forceinline__ float bf2f(uint16_t b){
  u32 u = ((u32)b) << 16; float f; __builtin_memcpy(&f, &u, 4); return f;
}
__device__ __forceinline__ uint16_t f2bf(float f){
  u32 u; __builtin_memcpy(&u, &f, 4);
  u = u + 0x7fffu + ((u >> 16) & 1u);           // round-nearest-even
  return (uint16_t)(u >> 16);
}
__device__ __forceinline__ float fsig(float x){ return 1.f / (1.f + __expf(-x)); }
__device__ __forceinline__ float ftanh(float x){
  float xc = fminf(fmaxf(x, -15.f), 15.f);
  float e  = __expf(2.f * xc);
  return (e - 1.f) / (e + 1.f);
}
__device__ __forceinline__ void gl_lds16(const void* g, void* l){
  __builtin_amdgcn_global_load_lds((const __attribute__((address_space(1))) void*)g,
                                   (__attribute__((address_space(3))) void*)l, 16, 0, 0);
}
__device__ __forceinline__ u32 umaxv(u32 a, u32 b){ return a > b ? a : b; }

// ---------------- int64-vs-int32 token layout detector ----------------
__global__ void detect_i64(const u32* __restrict__ x, u32* __restrict__ flag){
  int gid = blockIdx.x * 256 + threadIdx.x;     // 0..32767
  u32 v = x[1 + 2 * gid];
  if (v != 0u) atomicOr(flag, 1u);              // 1 -> int32 layout
}

// ---------------- embedding gather + cast to bf16 ----------------
__global__ __launch_bounds__(256) void gather_embed(
    const u32* __restrict__ x, const float* __restrict__ emb,
    uint16_t* __restrict__ e, const u32* __restrict__ flag){
  int row = blockIdx.x * 8 + (threadIdx.x >> 5);      // 0..65535
  int c0  = (threadIdx.x & 31) * 16;
  u32 tok = (*flag != 0u) ? x[row] : x[2 * row];
  const float* s = emb + (size_t)tok * 512 + c0;
  fl4 a = *(const fl4*)(s);
  fl4 b = *(const fl4*)(s + 4);
  fl4 c = *(const fl4*)(s + 8);
  fl4 d = *(const fl4*)(s + 12);
  u32x4 q0 = { (u32)f2bf(a.x) | ((u32)f2bf(a.y) << 16),
               (u32)f2bf(a.z) | ((u32)f2bf(a.w) << 16),
               (u32)f2bf(b.x) | ((u32)f2bf(b.y) << 16),
               (u32)f2bf(b.z) | ((u32)f2bf(b.w) << 16) };
  u32x4 q1 = { (u32)f2bf(c.x) | ((u32)f2bf(c.y) << 16),
               (u32)f2bf(c.z) | ((u32)f2bf(c.w) << 16),
               (u32)f2bf(d.x) | ((u32)f2bf(d.y) << 16),
               (u32)f2bf(d.z) | ((u32)f2bf(d.w) << 16) };
  *(u32x4*)(e + (size_t)row * 512 + c0)     = q0;
  *(u32x4*)(e + (size_t)row * 512 + c0 + 8) = q1;
}

// ---------------- weight prep: w_ih->bf16, w_hh->hi/lo bf16, bias sum ----------------
__global__ __launch_bounds__(256) void prep_w(
    const float* __restrict__ w_ih, const float* __restrict__ w_hh,
    const float* __restrict__ b_ih, const float* __restrict__ b_hh,
    uint16_t* __restrict__ wih, uint16_t* __restrict__ whi,
    uint16_t* __restrict__ wlo, float* __restrict__ bias){
  int bidx = blockIdx.x, t = threadIdx.x;
  if (bidx < 512){
    size_t i0 = (size_t)bidx * 2048 + t * 8;
    fl4 a = *(const fl4*)(w_ih + i0), b = *(const fl4*)(w_ih + i0 + 4);
    u32x4 q = { (u32)f2bf(a.x) | ((u32)f2bf(a.y) << 16),
                (u32)f2bf(a.z) | ((u32)f2bf(a.w) << 16),
                (u32)f2bf(b.x) | ((u32)f2bf(b.y) << 16),
                (u32)f2bf(b.z) | ((u32)f2bf(b.w) << 16) };
    *(u32x4*)(wih + i0) = q;
  } else if (bidx < 1024){
    size_t i0 = (size_t)(bidx - 512) * 2048 + t * 8;
    fl4 a = *(const fl4*)(w_hh + i0), b = *(const fl4*)(w_hh + i0 + 4);
    float v[8] = {a.x,a.y,a.z,a.w,b.x,b.y,b.z,b.w};
    uint16_t hi[8], lo[8];
    #pragma unroll
    for (int j = 0; j < 8; ++j){
      hi[j] = f2bf(v[j]);
      lo[j] = f2bf(v[j] - bf2f(hi[j]));
    }
    u32x4 qh = { (u32)hi[0]|((u32)hi[1]<<16), (u32)hi[2]|((u32)hi[3]<<16),
                 (u32)hi[4]|((u32)hi[5]<<16), (u32)hi[6]|((u32)hi[7]<<16) };
    u32x4 ql = { (u32)lo[0]|((u32)lo[1]<<16), (u32)lo[2]|((u32)lo[3]<<16),
                 (u32)lo[4]|((u32)lo[5]<<16), (u32)lo[6]|((u32)lo[7]<<16) };
    *(u32x4*)(whi + i0) = qh;
    *(u32x4*)(wlo + i0) = ql;
  } else {
    int i0 = t * 8;
    #pragma unroll
    for (int j = 0; j < 8; ++j) bias[i0 + j] = b_ih[i0 + j] + b_hh[i0 + j];
  }
}

// ---------------- x_proj GEMM: [65536x512]bf16 @ [2048x512]^T bf16 -> bf16 ----------------
__global__ __launch_bounds__(256,1) void gemm_xproj(
    const uint16_t* __restrict__ A, const uint16_t* __restrict__ Bw,
    uint16_t* __restrict__ C){
  __shared__ uint16_t As[128 * 64];
  __shared__ uint16_t Bs[128 * 64];
  int m0 = blockIdx.x * 128, n0 = blockIdx.y * 128;
  int tid = threadIdx.x, wid = tid >> 6, l = tid & 63;
  int wm = (wid >> 1) * 64, wn = (wid & 1) * 64;
  f32x4 zz = {0.f, 0.f, 0.f, 0.f};
  f32x4 acc[4][4];
  #pragma unroll
  for (int i = 0; i < 4; ++i)
    #pragma unroll
    for (int j = 0; j < 4; ++j) acc[i][j] = zz;
  const uint16_t* Ap = A  + (size_t)m0 * 512;
  const uint16_t* Bp = Bw + (size_t)n0 * 512;
  for (int kt = 0; kt < 8; ++kt){
    __syncthreads();
    #pragma unroll
    for (int i = 0; i < 4; ++i){
      int c = (i * 4 + wid) * 64 + l;       // 0..1023 chunk (16B) index
      int row = c >> 3, col = c & 7;
      int scol = col ^ (row & 7);           // XOR-swizzle via pre-swizzled source
      gl_lds16(Ap + (size_t)row * 512 + kt * 64 + scol * 8, &As[c * 8]);
      gl_lds16(Bp + (size_t)row * 512 + kt * 64 + scol * 8, &Bs[c * 8]);
    }
    __syncthreads();
    #pragma unroll
    for (int kk = 0; kk < 2; ++kk){
      bf16x8 af[4], bfr[4];
      #pragma unroll
      for (int i = 0; i < 4; ++i){
        int ra = wm + i * 16 + (l & 15);
        int rb = wn + i * 16 + (l & 15);
        int ci = kk * 4 + (l >> 4);
        af[i]  = *(const bf16x8*)((const char*)As + (size_t)ra * 128 + ((ci ^ (ra & 7)) << 4));
        bfr[i] = *(const bf16x8*)((const char*)Bs + (size_t)rb * 128 + ((ci ^ (rb & 7)) << 4));
      }
      #pragma unroll
      for (int mi = 0; mi < 4; ++mi)
        #pragma unroll
        for (int ni = 0; ni < 4; ++ni)
          acc[mi][ni] = __builtin_amdgcn_mfma_f32_16x16x32_bf16(af[mi], bfr[ni], acc[mi][ni], 0, 0, 0);
    }
  }
  #pragma unroll
  for (int mi = 0; mi < 4; ++mi)
    #pragma unroll
    for (int ni = 0; ni < 4; ++ni)
      #pragma unroll
      for (int r = 0; r < 4; ++r){
        int m = m0 + wm + mi * 16 + (l >> 4) * 4 + r;
        int n = n0 + wn + ni * 16 + (l & 15);
        C[(size_t)m * 2048 + n] = f2bf(acc[mi][ni][r]);
      }
}

// ---------------- persistent LSTM recurrence (self-validating data, zero flags) ----------------
// 128 WGs = 4 batch-groups x 32 hidden-slices. h stored as packed(hi|lo bf16) + epoch
// code ((t>>1)&1)<<30. Valid packed top-16 is in [0,0x3F81)u[0x8000,0xBF81), so epoch-0
// range, epoch-1 range (+0x4000_0000), and the 0xBF memset pattern are pairwise disjoint:
// ((v - eoff) & 0x7fffffff) < 0x3f810000 iff v is step-correct data. Double-buffer
// overwrite is safe without flags: producing h(t) requires having read ALL of h(t-1),
// which transitively means every WG finished reading h(t-2) (the slot being clobbered).
__global__ __launch_bounds__(256,1) void lstm_rec(
    const uint16_t* __restrict__ xp, const uint16_t* __restrict__ whi,
    const uint16_t* __restrict__ wlo, const float* __restrict__ bias,
    u32* __restrict__ hbuf){
  int bid = blockIdx.x;
  int g = bid & 3;                  // group
  int slice = bid >> 2;             // 0..31
  int tid = threadIdx.x, wid = tid >> 6, l = tid & 63;
  int n_local = wid * 16 + (l & 15);
  int u = slice * 16 + (n_local >> 2);
  int gate = n_local & 3;           // 0:i 1:f 2:g 3:o
  int grow = gate * 512 + u;        // gate row in [0,2048)
  int bquad = (l >> 4) * 4;         // batch base for D rows

  bf16x8 Bhi[16], Blo[16];
  {
    const uint16_t* ph = whi + (size_t)grow * 512 + (l >> 4) * 8;
    const uint16_t* pl = wlo + (size_t)grow * 512 + (l >> 4) * 8;
    #pragma unroll
    for (int ks = 0; ks < 16; ++ks){
      Bhi[ks] = *(const bf16x8*)(ph + ks * 32);
      Blo[ks] = *(const bf16x8*)(pl + ks * 32);
    }
  }
  float biasr = bias[grow];
  float c_[4] = {0.f, 0.f, 0.f, 0.f};
  u32* hb0 = hbuf + (size_t)(g * 2 + 0) * (16 * 512);
  u32* hb1 = hbuf + (size_t)(g * 2 + 1) * (16 * 512);
  const uint16_t* xpb = xp + (size_t)(g * 16 + bquad) * T_ * G4H + grow;
  int alive = 500000;               // dead-man poll budget (whole kernel)

  for (int t = 0; t < T_; ++t){
    uint16_t xpr[4];                // issued early -> overlaps the poll
    #pragma unroll
    for (int r = 0; r < 4; ++r)
      xpr[r] = xpb[(size_t)r * T_ * G4H + (size_t)t * G4H];
    f32x4 acc = {0.f, 0.f, 0.f, 0.f};
    if (t > 0){
      // lane (l&15) = batch row, k-column block = (l>>4)*8 + ks*32
      const u64* hsrc = (const u64*)(((t & 1) ? hb0 : hb1) + (l & 15) * 512 + (l >> 4) * 8);
      u32 eoffc = (u32)(((t - 1) >> 1) & 1) << 30;
      u64 d[64];
      #pragma unroll
      for (int k = 0; k < 64; ++k)
        d[k] = __hip_atomic_load(hsrc + (k >> 2) * 16 + (k & 3),
                                 __ATOMIC_RELAXED, __HIP_MEMORY_SCOPE_AGENT);
      for (;;){
        u32 m = 0;
        #pragma unroll
        for (int k = 0; k < 64; ++k){
          u32 wa = ((u32)d[k]         - eoffc) & 0x7fffffffu;
          u32 wb = ((u32)(d[k] >> 32) - eoffc) & 0x7fffffffu;
          m = umaxv(m, umaxv(wa, wb));
        }
        if (__all(m < 0x3f810000u)) break;
        if (--alive < 0) break;
        #pragma unroll
        for (int k = 0; k < 64; ++k)
          d[k] = __hip_atomic_load(hsrc + (k >> 2) * 16 + (k & 3),
                                   __ATOMIC_RELAXED, __HIP_MEMORY_SCOPE_AGENT);
      }
      #pragma unroll
      for (int ks = 0; ks < 16; ++ks){
        u32 q0 = (u32)d[ks*4+0] - eoffc, q1 = (u32)(d[ks*4+0] >> 32) - eoffc;
        u32 q2 = (u32)d[ks*4+1] - eoffc, q3 = (u32)(d[ks*4+1] >> 32) - eoffc;
        u32 q4 = (u32)d[ks*4+2] - eoffc, q5 = (u32)(d[ks*4+2] >> 32) - eoffc;
        u32 q6 = (u32)d[ks*4+3] - eoffc, q7 = (u32)(d[ks*4+3] >> 32) - eoffc;
        u32x4 H = { (q0 >> 16) | (q1 & 0xffff0000u), (q2 >> 16) | (q3 & 0xffff0000u),
                    (q4 >> 16) | (q5 & 0xffff0000u), (q6 >> 16) | (q7 & 0xffff0000u) };
        u32x4 L = { (q0 & 0xffffu) | (q1 << 16), (q2 & 0xffffu) | (q3 << 16),
                    (q4 & 0xffffu) | (q5 << 16), (q6 & 0xffffu) | (q7 << 16) };
        bf16x8 ah, al;
        __builtin_memcpy(&ah, &H, 16);
        __builtin_memcpy(&al, &L, 16);
        acc = __builtin_amdgcn_mfma_f32_16x16x32_bf16(ah, Bhi[ks], acc, 0, 0, 0);
        acc = __builtin_amdgcn_mfma_f32_16x16x32_bf16(al, Bhi[ks], acc, 0, 0, 0);
        acc = __builtin_amdgcn_mfma_f32_16x16x32_bf16(ah, Blo[ks], acc, 0, 0, 0);
      }
    }
    // activations + state update (each 4-lane quad holds i,f,g,o of one unit)
    float hn[4];
    int qb = l & ~3;
    #pragma unroll
    for (int r = 0; r < 4; ++r){
      float pre = acc[r] + bf2f(xpr[r]) + biasr;
      float gi = __shfl(pre, qb + 0, 64);
      float gf = __shfl(pre, qb + 1, 64);
      float gg = __shfl(pre, qb + 2, 64);
      float go = __shfl(pre, qb + 3, 64);
      float i_ = fsig(gi), f_ = fsig(gf), g_ = ftanh(gg), o_ = fsig(go);
      c_[r] = f_ * c_[r] + i_ * g_;
      hn[r] = o_ * ftanh(c_[r]);
    }
    if ((l & 3) == 0){
      u32 eoffp = (u32)((t >> 1) & 1) << 30;
      u32* dst = ((t & 1) ? hb1 : hb0) + u;
      #pragma unroll
      for (int r = 0; r < 4; ++r){
        uint16_t hi = f2bf(hn[r]);
        uint16_t lo = f2bf(hn[r] - bf2f(hi));
        u32 packed = (((u32)hi << 16) | (u32)lo) + eoffp;
        __hip_atomic_store(dst + (size_t)(bquad + r) * 512, packed,
                           __ATOMIC_RELAXED, __HIP_MEMORY_SCOPE_AGENT);
      }
    }
  }
}

// ---------------- final head: out[64][2] = h_last @ w_out^T + b_out ----------------
__global__ void final_proj(const u32* __restrict__ hbuf, const float* __restrict__ w_out,
                           const float* __restrict__ b_out, float* __restrict__ out){
  int b = blockIdx.x;               // 0..63
  int g = b >> 4, bl = b & 15;
  const u32* hp = hbuf + (size_t)(g * 2 + 1) * (16 * 512) + bl * 512;  // t=1023 slot 1
  int tid = threadIdx.x;            // 64 threads
  float p0 = 0.f, p1 = 0.f;
  #pragma unroll
  for (int j = 0; j < 8; ++j){
    int k = tid * 8 + j;
    u32 pk = hp[k] - 0x40000000u;   // t=1023 epoch ((1023>>1)&1)=1
    float h = bf2f((uint16_t)(pk >> 16)) + bf2f((uint16_t)(pk & 0xffffu));
    p0 += h * w_out[k];
    p1 += h * w_out[512 + k];
  }
  #pragma unroll
  for (int off = 32; off > 0; off >>= 1){
    p0 += __shfl_down(p0, off, 64);
    p1 += __shfl_down(p1, off, 64);
  }
  if (tid == 0){
    out[b * 2 + 0] = p0 + b_out[0];
    out[b * 2 + 1] = p1 + b_out[1];
  }
}

extern "C" void kernel_launch(void* const* d_in, const int* in_sizes, int n_in,
                              void* d_out, int out_size, void* d_ws, size_t ws_size,
                              hipStream_t stream){
  const u32*   x     = (const u32*)d_in[0];
  const float* emb   = (const float*)d_in[1];
  const float* w_ih  = (const float*)d_in[2];
  const float* w_hh  = (const float*)d_in[3];
  const float* b_ih  = (const float*)d_in[4];
  const float* b_hh  = (const float*)d_in[5];
  const float* w_out = (const float*)d_in[6];
  const float* b_out = (const float*)d_in[7];
  char* ws = (char*)d_ws;

  uint16_t* e     = (uint16_t*)(ws);                             // 64 MiB (dead after gemm)
  uint16_t* xp    = (uint16_t*)(ws + 67108864ull);               // 256 MiB
  uint16_t* wih   = (uint16_t*)(ws + 335544320ull);              // 2 MiB
  uint16_t* whi   = (uint16_t*)(ws + 337641472ull);              // 2 MiB
  uint16_t* wlo   = (uint16_t*)(ws + 339738624ull);              // 2 MiB
  float*    bias  = (float*)   (ws + 341835776ull);              // 8 KiB
  u32*      flagw = (u32*)     (ws + 341843968ull);              // 4 B (i64 detect)
  u32*      hbuf  = (u32*)     (ws + 341901312ull);              // 256 KiB

  hipMemsetAsync(flagw, 0, 4, stream);
  hipMemsetAsync(hbuf, 0xBF, 4ull * 8 * 16 * 512, stream);       // invalid in both epochs
  detect_i64  <<<128, 256, 0, stream>>>(x, flagw);
  gather_embed<<<8192, 256, 0, stream>>>(x, emb, e, flagw);
  prep_w      <<<1025, 256, 0, stream>>>(w_ih, w_hh, b_ih, b_hh, wih, whi, wlo, bias);
  gemm_xproj  <<<dim3(512, 16), 256, 0, stream>>>(e, wih, xp);
  lstm_rec    <<<128, 256, 0, stream>>>(xp, whi, wlo, bias, hbuf);
  final_proj  <<<64, 64, 0, stream>>>(hbuf, w_out, b_out, (float*)d_out);
}

// Round 4
// 6142.778 us; speedup vs baseline: 3.4871x; 3.4871x over previous
//
#include <hip/hip_runtime.h>
#include <hip/hip_bf16.h>
#include <stdint.h>

typedef __bf16   bf16x8 __attribute__((ext_vector_type(8)));
typedef float    f32x4  __attribute__((ext_vector_type(4)));
typedef float    fl4    __attribute__((ext_vector_type(4)));
typedef uint32_t u32;
typedef unsigned long long u64;
typedef uint32_t u32x4  __attribute__((ext_vector_type(4)));

#define T_    1024
#define G4H   2048

__device__ __forceinline__ float bf2f(uint16_t b){
  u32 u = ((u32)b) << 16; float f; __builtin_memcpy(&f, &u, 4); return f;
}
__device__ __forceinline__ uint16_t f2bf(float f){
  u32 u; __builtin_memcpy(&u, &f, 4);
  u = u + 0x7fffu + ((u >> 16) & 1u);           // round-nearest-even
  return (uint16_t)(u >> 16);
}
__device__ __forceinline__ float fsig(float x){ return 1.f / (1.f + __expf(-x)); }
__device__ __forceinline__ float ftanh(float x){
  float xc = fminf(fmaxf(x, -15.f), 15.f);
  float e  = __expf(2.f * xc);
  return (e - 1.f) / (e + 1.f);
}
__device__ __forceinline__ void gl_lds16(const void* g, void* l){
  __builtin_amdgcn_global_load_lds((const __attribute__((address_space(1))) void*)g,
                                   (__attribute__((address_space(3))) void*)l, 16, 0, 0);
}
__device__ __forceinline__ u32 umaxv(u32 a, u32 b){ return a > b ? a : b; }

// ---------------- int64-vs-int32 token layout detector ----------------
__global__ void detect_i64(const u32* __restrict__ x, u32* __restrict__ flag){
  int gid = blockIdx.x * 256 + threadIdx.x;     // 0..32767
  u32 v = x[1 + 2 * gid];
  if (v != 0u) atomicOr(flag, 1u);              // 1 -> int32 layout
}

// ---------------- embedding gather + cast to bf16 ----------------
__global__ __launch_bounds__(256) void gather_embed(
    const u32* __restrict__ x, const float* __restrict__ emb,
    uint16_t* __restrict__ e, const u32* __restrict__ flag){
  int row = blockIdx.x * 8 + (threadIdx.x >> 5);      // 0..65535
  int c0  = (threadIdx.x & 31) * 16;
  u32 tok = (*flag != 0u) ? x[row] : x[2 * row];
  const float* s = emb + (size_t)tok * 512 + c0;
  fl4 a = *(const fl4*)(s);
  fl4 b = *(const fl4*)(s + 4);
  fl4 c = *(const fl4*)(s + 8);
  fl4 d = *(const fl4*)(s + 12);
  u32x4 q0 = { (u32)f2bf(a.x) | ((u32)f2bf(a.y) << 16),
               (u32)f2bf(a.z) | ((u32)f2bf(a.w) << 16),
               (u32)f2bf(b.x) | ((u32)f2bf(b.y) << 16),
               (u32)f2bf(b.z) | ((u32)f2bf(b.w) << 16) };
  u32x4 q1 = { (u32)f2bf(c.x) | ((u32)f2bf(c.y) << 16),
               (u32)f2bf(c.z) | ((u32)f2bf(c.w) << 16),
               (u32)f2bf(d.x) | ((u32)f2bf(d.y) << 16),
               (u32)f2bf(d.z) | ((u32)f2bf(d.w) << 16) };
  *(u32x4*)(e + (size_t)row * 512 + c0)     = q0;
  *(u32x4*)(e + (size_t)row * 512 + c0 + 8) = q1;
}

// ---------------- weight prep: w_ih->bf16, w_hh->hi/lo bf16, bias sum ----------------
__global__ __launch_bounds__(256) void prep_w(
    const float* __restrict__ w_ih, const float* __restrict__ w_hh,
    const float* __restrict__ b_ih, const float* __restrict__ b_hh,
    uint16_t* __restrict__ wih, uint16_t* __restrict__ whi,
    uint16_t* __restrict__ wlo, float* __restrict__ bias){
  int bidx = blockIdx.x, t = threadIdx.x;
  if (bidx < 512){
    size_t i0 = (size_t)bidx * 2048 + t * 8;
    fl4 a = *(const fl4*)(w_ih + i0), b = *(const fl4*)(w_ih + i0 + 4);
    u32x4 q = { (u32)f2bf(a.x) | ((u32)f2bf(a.y) << 16),
                (u32)f2bf(a.z) | ((u32)f2bf(a.w) << 16),
                (u32)f2bf(b.x) | ((u32)f2bf(b.y) << 16),
                (u32)f2bf(b.z) | ((u32)f2bf(b.w) << 16) };
    *(u32x4*)(wih + i0) = q;
  } else if (bidx < 1024){
    size_t i0 = (size_t)(bidx - 512) * 2048 + t * 8;
    fl4 a = *(const fl4*)(w_hh + i0), b = *(const fl4*)(w_hh + i0 + 4);
    float v[8] = {a.x,a.y,a.z,a.w,b.x,b.y,b.z,b.w};
    uint16_t hi[8], lo[8];
    #pragma unroll
    for (int j = 0; j < 8; ++j){
      hi[j] = f2bf(v[j]);
      lo[j] = f2bf(v[j] - bf2f(hi[j]));
    }
    u32x4 qh = { (u32)hi[0]|((u32)hi[1]<<16), (u32)hi[2]|((u32)hi[3]<<16),
                 (u32)hi[4]|((u32)hi[5]<<16), (u32)hi[6]|((u32)hi[7]<<16) };
    u32x4 ql = { (u32)lo[0]|((u32)lo[1]<<16), (u32)lo[2]|((u32)lo[3]<<16),
                 (u32)lo[4]|((u32)lo[5]<<16), (u32)lo[6]|((u32)lo[7]<<16) };
    *(u32x4*)(whi + i0) = qh;
    *(u32x4*)(wlo + i0) = ql;
  } else {
    int i0 = t * 8;
    #pragma unroll
    for (int j = 0; j < 8; ++j) bias[i0 + j] = b_ih[i0 + j] + b_hh[i0 + j];
  }
}

// ---------------- x_proj GEMM: [65536x512]bf16 @ [2048x512]^T bf16 -> bf16 ----------------
__global__ __launch_bounds__(256,1) void gemm_xproj(
    const uint16_t* __restrict__ A, const uint16_t* __restrict__ Bw,
    uint16_t* __restrict__ C){
  __shared__ uint16_t As[128 * 64];
  __shared__ uint16_t Bs[128 * 64];
  int m0 = blockIdx.x * 128, n0 = blockIdx.y * 128;
  int tid = threadIdx.x, wid = tid >> 6, l = tid & 63;
  int wm = (wid >> 1) * 64, wn = (wid & 1) * 64;
  f32x4 zz = {0.f, 0.f, 0.f, 0.f};
  f32x4 acc[4][4];
  #pragma unroll
  for (int i = 0; i < 4; ++i)
    #pragma unroll
    for (int j = 0; j < 4; ++j) acc[i][j] = zz;
  const uint16_t* Ap = A  + (size_t)m0 * 512;
  const uint16_t* Bp = Bw + (size_t)n0 * 512;
  for (int kt = 0; kt < 8; ++kt){
    __syncthreads();
    #pragma unroll
    for (int i = 0; i < 4; ++i){
      int c = (i * 4 + wid) * 64 + l;       // 0..1023 chunk (16B) index
      int row = c >> 3, col = c & 7;
      int scol = col ^ (row & 7);           // XOR-swizzle via pre-swizzled source
      gl_lds16(Ap + (size_t)row * 512 + kt * 64 + scol * 8, &As[c * 8]);
      gl_lds16(Bp + (size_t)row * 512 + kt * 64 + scol * 8, &Bs[c * 8]);
    }
    __syncthreads();
    #pragma unroll
    for (int kk = 0; kk < 2; ++kk){
      bf16x8 af[4], bfr[4];
      #pragma unroll
      for (int i = 0; i < 4; ++i){
        int ra = wm + i * 16 + (l & 15);
        int rb = wn + i * 16 + (l & 15);
        int ci = kk * 4 + (l >> 4);
        af[i]  = *(const bf16x8*)((const char*)As + (size_t)ra * 128 + ((ci ^ (ra & 7)) << 4));
        bfr[i] = *(const bf16x8*)((const char*)Bs + (size_t)rb * 128 + ((ci ^ (rb & 7)) << 4));
      }
      #pragma unroll
      for (int mi = 0; mi < 4; ++mi)
        #pragma unroll
        for (int ni = 0; ni < 4; ++ni)
          acc[mi][ni] = __builtin_amdgcn_mfma_f32_16x16x32_bf16(af[mi], bfr[ni], acc[mi][ni], 0, 0, 0);
    }
  }
  #pragma unroll
  for (int mi = 0; mi < 4; ++mi)
    #pragma unroll
    for (int ni = 0; ni < 4; ++ni)
      #pragma unroll
      for (int r = 0; r < 4; ++r){
        int m = m0 + wm + mi * 16 + (l >> 4) * 4 + r;
        int n = n0 + wn + ni * 16 + (l & 15);
        C[(size_t)m * 2048 + n] = f2bf(acc[mi][ni][r]);
      }
}

// ---------------- persistent LSTM recurrence ----------------
// Self-validating epoch-coded h (no fences/flags) + once-per-WG LDS staging.
// Each thread owns a 128B slice of the group's packed h: 16 parallel u64 bypass
// loads, per-thread validity check (epoch ((t>>1)&1)<<30 embedded; valid top-16
// ranges and 0xBF memset are pairwise disjoint), retry only own slice. Unpack
// hi/lo -> XOR-swizzled ds_write -> one __syncthreads -> MFMA from LDS.
// Single LDS buffer is safe: reaching step t+1's ds_write requires validating
// h(t), which requires every wave in this WG to have stored h(t), which happens
// after their step-t LDS reads completed.
__global__ __launch_bounds__(256,1) void lstm_rec(
    const uint16_t* __restrict__ xp, const uint16_t* __restrict__ whi,
    const uint16_t* __restrict__ wlo, const float* __restrict__ bias,
    u32* __restrict__ hbuf){
  int bid = blockIdx.x;
  int g = bid & 3;                  // group
  int slice = bid >> 2;             // 0..31
  int tid = threadIdx.x, wid = tid >> 6, l = tid & 63;
  int n_local = wid * 16 + (l & 15);
  int u = slice * 16 + (n_local >> 2);
  int gate = n_local & 3;           // 0:i 1:f 2:g 3:o
  int grow = gate * 512 + u;        // gate row in [0,2048)
  int bquad = (l >> 4) * 4;         // batch base for D rows

  bf16x8 Bhi[16], Blo[16];
  {
    const uint16_t* ph = whi + (size_t)grow * 512 + (l >> 4) * 8;
    const uint16_t* pl = wlo + (size_t)grow * 512 + (l >> 4) * 8;
    #pragma unroll
    for (int ks = 0; ks < 16; ++ks){
      Bhi[ks] = *(const bf16x8*)(ph + ks * 32);
      Blo[ks] = *(const bf16x8*)(pl + ks * 32);
    }
  }
  float biasr = bias[grow];
  float c_[4] = {0.f, 0.f, 0.f, 0.f};
  __shared__ uint16_t hhi[16 * 512];
  __shared__ uint16_t hlo[16 * 512];
  u32* hb0 = hbuf + (size_t)(g * 2 + 0) * (16 * 512);
  u32* hb1 = hbuf + (size_t)(g * 2 + 1) * (16 * 512);
  const uint16_t* xpb = xp + (size_t)(g * 16 + bquad) * T_ * G4H + grow;
  int alive = 2000000;              // dead-man retry budget (whole kernel)
  int sb = tid >> 4;                // staging: batch row 0..15
  int sc = tid & 15;                // staging: 32-unit block

  for (int t = 0; t < T_; ++t){
    uint16_t xpr[4];                // issued early -> overlaps the poll
    #pragma unroll
    for (int r = 0; r < 4; ++r)
      xpr[r] = xpb[(size_t)r * T_ * G4H + (size_t)t * G4H];
    if (t > 0){
      // ---- load own 128B slice (16 parallel u64), validate, retry own slice ----
      const u64* hsrc = (const u64*)(((t & 1) ? hb0 : hb1)) + sb * 256 + sc * 16;
      u32 eoffc = (u32)(((t - 1) >> 1) & 1) << 30;
      u64 d[16];
      #pragma unroll
      for (int j = 0; j < 16; ++j)
        d[j] = __hip_atomic_load(hsrc + j, __ATOMIC_RELAXED, __HIP_MEMORY_SCOPE_AGENT);
      for (;;){
        u32 m = 0;
        #pragma unroll
        for (int j = 0; j < 16; ++j){
          u32 wa = ((u32)d[j]         - eoffc) & 0x7fffffffu;
          u32 wb = ((u32)(d[j] >> 32) - eoffc) & 0x7fffffffu;
          m = umaxv(m, umaxv(wa, wb));
        }
        if (m < 0x3f810000u) break;
        if (--alive < 0) break;
        #pragma unroll
        for (int j = 0; j < 16; ++j)
          d[j] = __hip_atomic_load(hsrc + j, __ATOMIC_RELAXED, __HIP_MEMORY_SCOPE_AGENT);
      }
      // ---- unpack hi/lo, XOR-swizzled LDS write (4 chunks of 16B per array) ----
      #pragma unroll
      for (int cc = 0; cc < 4; ++cc){
        u32 H[4], L[4];
        #pragma unroll
        for (int q = 0; q < 4; ++q){
          u32 v0 = (u32)d[cc * 4 + q]         - eoffc;
          u32 v1 = (u32)(d[cc * 4 + q] >> 32) - eoffc;
          H[q] = (v0 >> 16)     | (v1 & 0xffff0000u);
          L[q] = (v0 & 0xffffu) | (v1 << 16);
        }
        int chunk = (sc * 4 + cc) ^ (sb & 7);
        u32x4 qh = {H[0], H[1], H[2], H[3]};
        u32x4 ql = {L[0], L[1], L[2], L[3]};
        *(u32x4*)((char*)hhi + sb * 1024 + chunk * 16) = qh;
        *(u32x4*)((char*)hlo + sb * 1024 + chunk * 16) = ql;
      }
    }
    __syncthreads();
    f32x4 acc = {0.f, 0.f, 0.f, 0.f};
    if (t > 0){
      int brow = l & 15;
      #pragma unroll
      for (int ks = 0; ks < 16; ++ks){
        int chunk = (ks * 4 + (l >> 4)) ^ (brow & 7);
        bf16x8 ah = *(const bf16x8*)((const char*)hhi + brow * 1024 + chunk * 16);
        bf16x8 al = *(const bf16x8*)((const char*)hlo + brow * 1024 + chunk * 16);
        acc = __builtin_amdgcn_mfma_f32_16x16x32_bf16(ah, Bhi[ks], acc, 0, 0, 0);
        acc = __builtin_amdgcn_mfma_f32_16x16x32_bf16(al, Bhi[ks], acc, 0, 0, 0);
        acc = __builtin_amdgcn_mfma_f32_16x16x32_bf16(ah, Blo[ks], acc, 0, 0, 0);
      }
    }
    // activations + state update (each 4-lane quad holds i,f,g,o of one unit)
    float hn[4];
    int qb = l & ~3;
    #pragma unroll
    for (int r = 0; r < 4; ++r){
      float pre = acc[r] + bf2f(xpr[r]) + biasr;
      float gi = __shfl(pre, qb + 0, 64);
      float gf = __shfl(pre, qb + 1, 64);
      float gg = __shfl(pre, qb + 2, 64);
      float go = __shfl(pre, qb + 3, 64);
      float i_ = fsig(gi), f_ = fsig(gf), g_ = ftanh(gg), o_ = fsig(go);
      c_[r] = f_ * c_[r] + i_ * g_;
      hn[r] = o_ * ftanh(c_[r]);
    }
    if ((l & 3) == 0){
      u32 eoffp = (u32)((t >> 1) & 1) << 30;
      u32* dst = ((t & 1) ? hb1 : hb0) + u;
      #pragma unroll
      for (int r = 0; r < 4; ++r){
        uint16_t hi = f2bf(hn[r]);
        uint16_t lo = f2bf(hn[r] - bf2f(hi));
        u32 packed = (((u32)hi << 16) | (u32)lo) + eoffp;
        __hip_atomic_store(dst + (size_t)(bquad + r) * 512, packed,
                           __ATOMIC_RELAXED, __HIP_MEMORY_SCOPE_AGENT);
      }
    }
  }
}

// ---------------- final head: out[64][2] = h_last @ w_out^T + b_out ----------------
__global__ void final_proj(const u32* __restrict__ hbuf, const float* __restrict__ w_out,
                           const float* __restrict__ b_out, float* __restrict__ out){
  int b = blockIdx.x;               // 0..63
  int g = b >> 4, bl = b & 15;
  const u32* hp = hbuf + (size_t)(g * 2 + 1) * (16 * 512) + bl * 512;  // t=1023 slot 1
  int tid = threadIdx.x;            // 64 threads
  float p0 = 0.f, p1 = 0.f;
  #pragma unroll
  for (int j = 0; j < 8; ++j){
    int k = tid * 8 + j;
    u32 pk = hp[k] - 0x40000000u;   // t=1023 epoch ((1023>>1)&1)=1
    float h = bf2f((uint16_t)(pk >> 16)) + bf2f((uint16_t)(pk & 0xffffu));
    p0 += h * w_out[k];
    p1 += h * w_out[512 + k];
  }
  #pragma unroll
  for (int off = 32; off > 0; off >>= 1){
    p0 += __shfl_down(p0, off, 64);
    p1 += __shfl_down(p1, off, 64);
  }
  if (tid == 0){
    out[b * 2 + 0] = p0 + b_out[0];
    out[b * 2 + 1] = p1 + b_out[1];
  }
}

extern "C" void kernel_launch(void* const* d_in, const int* in_sizes, int n_in,
                              void* d_out, int out_size, void* d_ws, size_t ws_size,
                              hipStream_t stream){
  const u32*   x     = (const u32*)d_in[0];
  const float* emb   = (const float*)d_in[1];
  const float* w_ih  = (const float*)d_in[2];
  const float* w_hh  = (const float*)d_in[3];
  const float* b_ih  = (const float*)d_in[4];
  const float* b_hh  = (const float*)d_in[5];
  const float* w_out = (const float*)d_in[6];
  const float* b_out = (const float*)d_in[7];
  char* ws = (char*)d_ws;

  uint16_t* e     = (uint16_t*)(ws);                             // 64 MiB (dead after gemm)
  uint16_t* xp    = (uint16_t*)(ws + 67108864ull);               // 256 MiB
  uint16_t* wih   = (uint16_t*)(ws + 335544320ull);              // 2 MiB
  uint16_t* whi   = (uint16_t*)(ws + 337641472ull);              // 2 MiB
  uint16_t* wlo   = (uint16_t*)(ws + 339738624ull);              // 2 MiB
  float*    bias  = (float*)   (ws + 341835776ull);              // 8 KiB
  u32*      flagw = (u32*)     (ws + 341843968ull);              // 4 B (i64 detect)
  u32*      hbuf  = (u32*)     (ws + 341901312ull);              // 256 KiB

  hipMemsetAsync(flagw, 0, 4, stream);
  hipMemsetAsync(hbuf, 0xBF, 4ull * 8 * 16 * 512, stream);       // invalid in both epochs
  detect_i64  <<<128, 256, 0, stream>>>(x, flagw);
  gather_embed<<<8192, 256, 0, stream>>>(x, emb, e, flagw);
  prep_w      <<<1025, 256, 0, stream>>>(w_ih, w_hh, b_ih, b_hh, wih, whi, wlo, bias);
  gemm_xproj  <<<dim3(512, 16), 256, 0, stream>>>(e, wih, xp);
  lstm_rec    <<<128, 256, 0, stream>>>(xp, whi, wlo, bias, hbuf);
  final_proj  <<<64, 64, 0, stream>>>(hbuf, w_out, b_out, (float*)d_out);
}

// Round 5
// 4840.710 us; speedup vs baseline: 4.4251x; 1.2690x over previous
//
#include <hip/hip_runtime.h>
#include <hip/hip_bf16.h>
#include <stdint.h>

typedef __bf16   bf16x8 __attribute__((ext_vector_type(8)));
typedef float    f32x4  __attribute__((ext_vector_type(4)));
typedef float    fl4    __attribute__((ext_vector_type(4)));
typedef uint32_t u32;
typedef unsigned long long u64;
typedef uint32_t u32x4  __attribute__((ext_vector_type(4)));

#define T_    1024
#define G4H   2048

__device__ __forceinline__ float bf2f(uint16_t b){
  u32 u = ((u32)b) << 16; float f; __builtin_memcpy(&f, &u, 4); return f;
}
__device__ __forceinline__ uint16_t f2bf(float f){
  u32 u; __builtin_memcpy(&u, &f, 4);
  u = u + 0x7fffu + ((u >> 16) & 1u);           // round-nearest-even
  return (uint16_t)(u >> 16);
}
__device__ __forceinline__ float fsig(float x){ return 1.f / (1.f + __expf(-x)); }
__device__ __forceinline__ float ftanh(float x){
  float xc = fminf(fmaxf(x, -15.f), 15.f);
  float e  = __expf(2.f * xc);
  return (e - 1.f) / (e + 1.f);
}
__device__ __forceinline__ void gl_lds16(const void* g, void* l){
  __builtin_amdgcn_global_load_lds((const __attribute__((address_space(1))) void*)g,
                                   (__attribute__((address_space(3))) void*)l, 16, 0, 0);
}
__device__ __forceinline__ u32 umaxv(u32 a, u32 b){ return a > b ? a : b; }

// ---------------- int64-vs-int32 token layout detector ----------------
__global__ void detect_i64(const u32* __restrict__ x, u32* __restrict__ flag){
  int gid = blockIdx.x * 256 + threadIdx.x;     // 0..32767
  u32 v = x[1 + 2 * gid];
  if (v != 0u) atomicOr(flag, 1u);              // 1 -> int32 layout
}

// ---------------- embedding gather + cast to bf16 ----------------
__global__ __launch_bounds__(256) void gather_embed(
    const u32* __restrict__ x, const float* __restrict__ emb,
    uint16_t* __restrict__ e, const u32* __restrict__ flag){
  int row = blockIdx.x * 8 + (threadIdx.x >> 5);      // 0..65535
  int c0  = (threadIdx.x & 31) * 16;
  u32 tok = (*flag != 0u) ? x[row] : x[2 * row];
  const float* s = emb + (size_t)tok * 512 + c0;
  fl4 a = *(const fl4*)(s);
  fl4 b = *(const fl4*)(s + 4);
  fl4 c = *(const fl4*)(s + 8);
  fl4 d = *(const fl4*)(s + 12);
  u32x4 q0 = { (u32)f2bf(a.x) | ((u32)f2bf(a.y) << 16),
               (u32)f2bf(a.z) | ((u32)f2bf(a.w) << 16),
               (u32)f2bf(b.x) | ((u32)f2bf(b.y) << 16),
               (u32)f2bf(b.z) | ((u32)f2bf(b.w) << 16) };
  u32x4 q1 = { (u32)f2bf(c.x) | ((u32)f2bf(c.y) << 16),
               (u32)f2bf(c.z) | ((u32)f2bf(c.w) << 16),
               (u32)f2bf(d.x) | ((u32)f2bf(d.y) << 16),
               (u32)f2bf(d.z) | ((u32)f2bf(d.w) << 16) };
  *(u32x4*)(e + (size_t)row * 512 + c0)     = q0;
  *(u32x4*)(e + (size_t)row * 512 + c0 + 8) = q1;
}

// ---------------- weight prep: w_ih->bf16, w_hh->hi/lo bf16, bias sum ----------------
__global__ __launch_bounds__(256) void prep_w(
    const float* __restrict__ w_ih, const float* __restrict__ w_hh,
    const float* __restrict__ b_ih, const float* __restrict__ b_hh,
    uint16_t* __restrict__ wih, uint16_t* __restrict__ whi,
    uint16_t* __restrict__ wlo, float* __restrict__ bias){
  int bidx = blockIdx.x, t = threadIdx.x;
  if (bidx < 512){
    size_t i0 = (size_t)bidx * 2048 + t * 8;
    fl4 a = *(const fl4*)(w_ih + i0), b = *(const fl4*)(w_ih + i0 + 4);
    u32x4 q = { (u32)f2bf(a.x) | ((u32)f2bf(a.y) << 16),
                (u32)f2bf(a.z) | ((u32)f2bf(a.w) << 16),
                (u32)f2bf(b.x) | ((u32)f2bf(b.y) << 16),
                (u32)f2bf(b.z) | ((u32)f2bf(b.w) << 16) };
    *(u32x4*)(wih + i0) = q;
  } else if (bidx < 1024){
    size_t i0 = (size_t)(bidx - 512) * 2048 + t * 8;
    fl4 a = *(const fl4*)(w_hh + i0), b = *(const fl4*)(w_hh + i0 + 4);
    float v[8] = {a.x,a.y,a.z,a.w,b.x,b.y,b.z,b.w};
    uint16_t hi[8], lo[8];
    #pragma unroll
    for (int j = 0; j < 8; ++j){
      hi[j] = f2bf(v[j]);
      lo[j] = f2bf(v[j] - bf2f(hi[j]));
    }
    u32x4 qh = { (u32)hi[0]|((u32)hi[1]<<16), (u32)hi[2]|((u32)hi[3]<<16),
                 (u32)hi[4]|((u32)hi[5]<<16), (u32)hi[6]|((u32)hi[7]<<16) };
    u32x4 ql = { (u32)lo[0]|((u32)lo[1]<<16), (u32)lo[2]|((u32)lo[3]<<16),
                 (u32)lo[4]|((u32)lo[5]<<16), (u32)lo[6]|((u32)lo[7]<<16) };
    *(u32x4*)(whi + i0) = qh;
    *(u32x4*)(wlo + i0) = ql;
  } else {
    int i0 = t * 8;
    #pragma unroll
    for (int j = 0; j < 8; ++j) bias[i0 + j] = b_ih[i0 + j] + b_hh[i0 + j];
  }
}

// ---------------- x_proj GEMM: [65536x512]bf16 @ [2048x512]^T bf16 -> bf16 ----------------
__global__ __launch_bounds__(256,1) void gemm_xproj(
    const uint16_t* __restrict__ A, const uint16_t* __restrict__ Bw,
    uint16_t* __restrict__ C){
  __shared__ uint16_t As[128 * 64];
  __shared__ uint16_t Bs[128 * 64];
  int m0 = blockIdx.x * 128, n0 = blockIdx.y * 128;
  int tid = threadIdx.x, wid = tid >> 6, l = tid & 63;
  int wm = (wid >> 1) * 64, wn = (wid & 1) * 64;
  f32x4 zz = {0.f, 0.f, 0.f, 0.f};
  f32x4 acc[4][4];
  #pragma unroll
  for (int i = 0; i < 4; ++i)
    #pragma unroll
    for (int j = 0; j < 4; ++j) acc[i][j] = zz;
  const uint16_t* Ap = A  + (size_t)m0 * 512;
  const uint16_t* Bp = Bw + (size_t)n0 * 512;
  for (int kt = 0; kt < 8; ++kt){
    __syncthreads();
    #pragma unroll
    for (int i = 0; i < 4; ++i){
      int c = (i * 4 + wid) * 64 + l;       // 0..1023 chunk (16B) index
      int row = c >> 3, col = c & 7;
      int scol = col ^ (row & 7);           // XOR-swizzle via pre-swizzled source
      gl_lds16(Ap + (size_t)row * 512 + kt * 64 + scol * 8, &As[c * 8]);
      gl_lds16(Bp + (size_t)row * 512 + kt * 64 + scol * 8, &Bs[c * 8]);
    }
    __syncthreads();
    #pragma unroll
    for (int kk = 0; kk < 2; ++kk){
      bf16x8 af[4], bfr[4];
      #pragma unroll
      for (int i = 0; i < 4; ++i){
        int ra = wm + i * 16 + (l & 15);
        int rb = wn + i * 16 + (l & 15);
        int ci = kk * 4 + (l >> 4);
        af[i]  = *(const bf16x8*)((const char*)As + (size_t)ra * 128 + ((ci ^ (ra & 7)) << 4));
        bfr[i] = *(const bf16x8*)((const char*)Bs + (size_t)rb * 128 + ((ci ^ (rb & 7)) << 4));
      }
      #pragma unroll
      for (int mi = 0; mi < 4; ++mi)
        #pragma unroll
        for (int ni = 0; ni < 4; ++ni)
          acc[mi][ni] = __builtin_amdgcn_mfma_f32_16x16x32_bf16(af[mi], bfr[ni], acc[mi][ni], 0, 0, 0);
    }
  }
  #pragma unroll
  for (int mi = 0; mi < 4; ++mi)
    #pragma unroll
    for (int ni = 0; ni < 4; ++ni)
      #pragma unroll
      for (int r = 0; r < 4; ++r){
        int m = m0 + wm + mi * 16 + (l >> 4) * 4 + r;
        int n = n0 + wn + ni * 16 + (l & 15);
        C[(size_t)m * 2048 + n] = f2bf(acc[mi][ni][r]);
      }
}

// ---------------- persistent LSTM recurrence ----------------
// Self-validating epoch-coded h (no fences/flags). Per step, each thread:
//  (1) spins on TWO 4B sentinels (one per producer WG feeding its 128B slice),
//      2 parallel asm loads + vmcnt(0) -> tiny poll traffic (no fabric congestion);
//  (2) one-shot 8x global_load_dwordx4 asm batch (parallel, 1 RTT), full epoch
//      validation, rare retry;
//  (3) unpack hi/lo -> sigma-swizzled ds_write_b128 (both read+write <=2-way
//      bank conflict: sb=tid&15 spans all rows per 16-lane phase,
//      sigma(r) = (r&7)^((r>>3)<<2)).
// Double-buffer overwrite safety needs no flags: producing h(t) requires having
// read all of h(t-1), transitively all WGs finished reading h(t-2).
__global__ __launch_bounds__(256,1) void lstm_rec(
    const uint16_t* __restrict__ xp, const uint16_t* __restrict__ whi,
    const uint16_t* __restrict__ wlo, const float* __restrict__ bias,
    u32* __restrict__ hbuf){
  int bid = blockIdx.x;
  int g = bid & 3;                  // group
  int slice = bid >> 2;             // 0..31
  int tid = threadIdx.x, wid = tid >> 6, l = tid & 63;
  int n_local = wid * 16 + (l & 15);
  int u = slice * 16 + (n_local >> 2);
  int gate = n_local & 3;           // 0:i 1:f 2:g 3:o
  int grow = gate * 512 + u;        // gate row in [0,2048)
  int bquad = (l >> 4) * 4;         // batch base for D rows

  bf16x8 Bhi[16], Blo[16];
  {
    const uint16_t* ph = whi + (size_t)grow * 512 + (l >> 4) * 8;
    const uint16_t* pl = wlo + (size_t)grow * 512 + (l >> 4) * 8;
    #pragma unroll
    for (int ks = 0; ks < 16; ++ks){
      Bhi[ks] = *(const bf16x8*)(ph + ks * 32);
      Blo[ks] = *(const bf16x8*)(pl + ks * 32);
    }
  }
  float biasr = bias[grow];
  float c_[4] = {0.f, 0.f, 0.f, 0.f};
  __shared__ uint16_t hhi[16 * 512];
  __shared__ uint16_t hlo[16 * 512];
  u32* hb0 = hbuf + (size_t)(g * 2 + 0) * (16 * 512);
  u32* hb1 = hbuf + (size_t)(g * 2 + 1) * (16 * 512);
  const uint16_t* xpb = xp + (size_t)(g * 16 + bquad) * T_ * G4H + grow;
  int alive = 1000000;              // dead-man retry budget (whole kernel)
  int sb = tid & 15;                // staging: batch row (spans all rows per phase)
  int sc = tid >> 4;                // staging: 32-u32 column block
  int ssig = (sb & 7) ^ ((sb >> 3) << 2);   // sigma(sb)
  int brow = l & 15;
  int rsig = (brow & 7) ^ ((brow >> 3) << 2);

  for (int t = 0; t < T_; ++t){
    uint16_t xpr[4];                // issued early -> overlaps the poll
    #pragma unroll
    for (int r = 0; r < 4; ++r)
      xpr[r] = xpb[(size_t)r * T_ * G4H + (size_t)t * G4H];
    if (t > 0){
      const u32* hrow = ((t & 1) ? hb0 : hb1) + sb * 512 + sc * 32;
      u64 av = (u64)(uintptr_t)hrow;
      u32 eoffc = (u32)(((t - 1) >> 1) & 1) << 30;
      // ---- (1) sentinel spin: units 32sc (producer 2sc) and 32sc+16 (2sc+1) ----
      for (;;){
        u32 s0, s1;
        asm volatile(
          "global_load_dword %0, %2, off sc0 sc1\n\t"
          "global_load_dword %1, %2, off offset:64 sc0 sc1\n\t"
          "s_waitcnt vmcnt(0)"
          : "=&v"(s0), "=&v"(s1) : "v"(av) : "memory");
        u32 wa = (s0 - eoffc) & 0x7fffffffu;
        u32 wb = (s1 - eoffc) & 0x7fffffffu;
        if (umaxv(wa, wb) < 0x3f810000u) break;
        if (--alive < 0) break;
      }
      // ---- (2) one-shot parallel 128B batch + full validation ----
      u32x4 q0, q1, q2, q3, q4, q5, q6, q7;
      for (;;){
        asm volatile(
          "global_load_dwordx4 %0, %8, off sc0 sc1\n\t"
          "global_load_dwordx4 %1, %8, off offset:16 sc0 sc1\n\t"
          "global_load_dwordx4 %2, %8, off offset:32 sc0 sc1\n\t"
          "global_load_dwordx4 %3, %8, off offset:48 sc0 sc1\n\t"
          "global_load_dwordx4 %4, %8, off offset:64 sc0 sc1\n\t"
          "global_load_dwordx4 %5, %8, off offset:80 sc0 sc1\n\t"
          "global_load_dwordx4 %6, %8, off offset:96 sc0 sc1\n\t"
          "global_load_dwordx4 %7, %8, off offset:112 sc0 sc1\n\t"
          "s_waitcnt vmcnt(0)"
          : "=&v"(q0), "=&v"(q1), "=&v"(q2), "=&v"(q3),
            "=&v"(q4), "=&v"(q5), "=&v"(q6), "=&v"(q7)
          : "v"(av) : "memory");
        u32 m = 0;
        #define VQ(Q) \
          m = umaxv(m, umaxv((Q.x - eoffc) & 0x7fffffffu, (Q.y - eoffc) & 0x7fffffffu)); \
          m = umaxv(m, umaxv((Q.z - eoffc) & 0x7fffffffu, (Q.w - eoffc) & 0x7fffffffu));
        VQ(q0) VQ(q1) VQ(q2) VQ(q3) VQ(q4) VQ(q5) VQ(q6) VQ(q7)
        #undef VQ
        if (m < 0x3f810000u) break;
        if (--alive < 0) break;
      }
      // ---- (3) unpack hi/lo, sigma-swizzled LDS write (4 b128 per array) ----
      u32 V[32];
      *(u32x4*)&V[0]  = q0; *(u32x4*)&V[4]  = q1;
      *(u32x4*)&V[8]  = q2; *(u32x4*)&V[12] = q3;
      *(u32x4*)&V[16] = q4; *(u32x4*)&V[20] = q5;
      *(u32x4*)&V[24] = q6; *(u32x4*)&V[28] = q7;
      u32 H[16], L[16];
      #pragma unroll
      for (int j = 0; j < 16; ++j){
        u32 a = V[2*j] - eoffc, b = V[2*j+1] - eoffc;
        H[j] = (a >> 16)      | (b & 0xffff0000u);
        L[j] = (a & 0xffffu)  | (b << 16);
      }
      #pragma unroll
      for (int cc = 0; cc < 4; ++cc){
        int slot = (sc * 4 + cc) ^ ssig;
        u32x4 qh = {H[4*cc], H[4*cc+1], H[4*cc+2], H[4*cc+3]};
        u32x4 ql = {L[4*cc], L[4*cc+1], L[4*cc+2], L[4*cc+3]};
        *(u32x4*)((char*)hhi + sb * 1024 + slot * 16) = qh;
        *(u32x4*)((char*)hlo + sb * 1024 + slot * 16) = ql;
      }
    }
    __syncthreads();
    f32x4 acc = {0.f, 0.f, 0.f, 0.f};
    if (t > 0){
      #pragma unroll
      for (int ks = 0; ks < 16; ++ks){
        int slot = (ks * 4 + (l >> 4)) ^ rsig;
        bf16x8 ah = *(const bf16x8*)((const char*)hhi + brow * 1024 + slot * 16);
        bf16x8 al = *(const bf16x8*)((const char*)hlo + brow * 1024 + slot * 16);
        acc = __builtin_amdgcn_mfma_f32_16x16x32_bf16(ah, Bhi[ks], acc, 0, 0, 0);
        acc = __builtin_amdgcn_mfma_f32_16x16x32_bf16(al, Bhi[ks], acc, 0, 0, 0);
        acc = __builtin_amdgcn_mfma_f32_16x16x32_bf16(ah, Blo[ks], acc, 0, 0, 0);
      }
    }
    // activations + state update (each 4-lane quad holds i,f,g,o of one unit)
    float hn[4];
    int qb = l & ~3;
    #pragma unroll
    for (int r = 0; r < 4; ++r){
      float pre = acc[r] + bf2f(xpr[r]) + biasr;
      float gi = __shfl(pre, qb + 0, 64);
      float gf = __shfl(pre, qb + 1, 64);
      float gg = __shfl(pre, qb + 2, 64);
      float go = __shfl(pre, qb + 3, 64);
      float i_ = fsig(gi), f_ = fsig(gf), g_ = ftanh(gg), o_ = fsig(go);
      c_[r] = f_ * c_[r] + i_ * g_;
      hn[r] = o_ * ftanh(c_[r]);
    }
    if ((l & 3) == 0){
      u32 eoffp = (u32)((t >> 1) & 1) << 30;
      u32* dst = ((t & 1) ? hb1 : hb0) + u;
      #pragma unroll
      for (int r = 0; r < 4; ++r){
        uint16_t hi = f2bf(hn[r]);
        uint16_t lo = f2bf(hn[r] - bf2f(hi));
        u32 packed = (((u32)hi << 16) | (u32)lo) + eoffp;
        __hip_atomic_store(dst + (size_t)(bquad + r) * 512, packed,
                           __ATOMIC_RELAXED, __HIP_MEMORY_SCOPE_AGENT);
      }
    }
    __syncthreads();                // LDS reads done before next step's overwrite
  }
}

// ---------------- final head: out[64][2] = h_last @ w_out^T + b_out ----------------
__global__ void final_proj(const u32* __restrict__ hbuf, const float* __restrict__ w_out,
                           const float* __restrict__ b_out, float* __restrict__ out){
  int b = blockIdx.x;               // 0..63
  int g = b >> 4, bl = b & 15;
  const u32* hp = hbuf + (size_t)(g * 2 + 1) * (16 * 512) + bl * 512;  // t=1023 slot 1
  int tid = threadIdx.x;            // 64 threads
  float p0 = 0.f, p1 = 0.f;
  #pragma unroll
  for (int j = 0; j < 8; ++j){
    int k = tid * 8 + j;
    u32 pk = hp[k] - 0x40000000u;   // t=1023 epoch ((1023>>1)&1)=1
    float h = bf2f((uint16_t)(pk >> 16)) + bf2f((uint16_t)(pk & 0xffffu));
    p0 += h * w_out[k];
    p1 += h * w_out[512 + k];
  }
  #pragma unroll
  for (int off = 32; off > 0; off >>= 1){
    p0 += __shfl_down(p0, off, 64);
    p1 += __shfl_down(p1, off, 64);
  }
  if (tid == 0){
    out[b * 2 + 0] = p0 + b_out[0];
    out[b * 2 + 1] = p1 + b_out[1];
  }
}

extern "C" void kernel_launch(void* const* d_in, const int* in_sizes, int n_in,
                              void* d_out, int out_size, void* d_ws, size_t ws_size,
                              hipStream_t stream){
  const u32*   x     = (const u32*)d_in[0];
  const float* emb   = (const float*)d_in[1];
  const float* w_ih  = (const float*)d_in[2];
  const float* w_hh  = (const float*)d_in[3];
  const float* b_ih  = (const float*)d_in[4];
  const float* b_hh  = (const float*)d_in[5];
  const float* w_out = (const float*)d_in[6];
  const float* b_out = (const float*)d_in[7];
  char* ws = (char*)d_ws;

  uint16_t* e     = (uint16_t*)(ws);                             // 64 MiB (dead after gemm)
  uint16_t* xp    = (uint16_t*)(ws + 67108864ull);               // 256 MiB
  uint16_t* wih   = (uint16_t*)(ws + 335544320ull);              // 2 MiB
  uint16_t* whi   = (uint16_t*)(ws + 337641472ull);              // 2 MiB
  uint16_t* wlo   = (uint16_t*)(ws + 339738624ull);              // 2 MiB
  float*    bias  = (float*)   (ws + 341835776ull);              // 8 KiB
  u32*      flagw = (u32*)     (ws + 341843968ull);              // 4 B (i64 detect)
  u32*      hbuf  = (u32*)     (ws + 341901312ull);              // 256 KiB

  hipMemsetAsync(flagw, 0, 4, stream);
  hipMemsetAsync(hbuf, 0xBF, 4ull * 8 * 16 * 512, stream);       // invalid in both epochs
  detect_i64  <<<128, 256, 0, stream>>>(x, flagw);
  gather_embed<<<8192, 256, 0, stream>>>(x, emb, e, flagw);
  prep_w      <<<1025, 256, 0, stream>>>(w_ih, w_hh, b_ih, b_hh, wih, whi, wlo, bias);
  gemm_xproj  <<<dim3(512, 16), 256, 0, stream>>>(e, wih, xp);
  lstm_rec    <<<128, 256, 0, stream>>>(xp, whi, wlo, bias, hbuf);
  final_proj  <<<64, 64, 0, stream>>>(hbuf, w_out, b_out, (float*)d_out);
}